// Round 11
// baseline (3557.175 us; speedup 1.0000x reference)
//
#include <hip/hip_runtime.h>
#include <cstdint>
#include <cstddef>

// ---------------- constants ----------------
#define MROWS   4096      // B*T
#define TSEQ    2048
#define DMODEL  1024
#define NHEAD   16
#define FFN     4096
#define NVOCAB  32000
#define NLAYER  4

typedef float  f32x4  __attribute__((ext_vector_type(4)));
typedef __bf16 bf16x8 __attribute__((ext_vector_type(8)));

__device__ __forceinline__ unsigned short f2bf(float f) {
    unsigned u = __builtin_bit_cast(unsigned, f);
    u += 0x7fffu + ((u >> 16) & 1u);
    return (unsigned short)(u >> 16);
}
__device__ __forceinline__ float bf2f(unsigned short u) {
    return __builtin_bit_cast(float, (unsigned)u << 16);
}

__device__ __forceinline__ float gelu_exact(float v) {
    return 0.5f * v * (1.0f + erff(v * 0.7071067811865476f));
}

// ---------------- embedding ----------------
__global__ __launch_bounds__(256) void embed_kernel(const int* __restrict__ idx,
                                                    const float* __restrict__ tok,
                                                    const float* __restrict__ pos,
                                                    float* __restrict__ x) {
    int row = blockIdx.x, tid = threadIdx.x;
    int token = idx[row];
    int t = row & (TSEQ - 1);
    float4 a = ((const float4*)(tok + (size_t)token * DMODEL))[tid];
    float4 p = ((const float4*)(pos + (size_t)t * DMODEL))[tid];
    a.x += p.x; a.y += p.y; a.z += p.z; a.w += p.w;
    ((float4*)(x + (size_t)row * DMODEL))[tid] = a;
}

// ---------------- LayerNorm fp32 in -> bf16 out ----------------
__global__ __launch_bounds__(256) void ln_kernel(const float* __restrict__ x,
                                                 const float* __restrict__ g,
                                                 const float* __restrict__ b,
                                                 unsigned short* __restrict__ out) {
    int row = blockIdx.x, tid = threadIdx.x;
    float4 v = ((const float4*)(x + (size_t)row * DMODEL))[tid];
    float s1 = v.x + v.y + v.z + v.w;
    float s2 = v.x * v.x + v.y * v.y + v.z * v.z + v.w * v.w;
    for (int s = 32; s; s >>= 1) { s1 += __shfl_xor(s1, s); s2 += __shfl_xor(s2, s); }
    __shared__ float red[8];
    int lane = tid & 63, w = tid >> 6;
    if (lane == 0) { red[w] = s1; red[4 + w] = s2; }
    __syncthreads();
    s1 = red[0] + red[1] + red[2] + red[3];
    s2 = red[4] + red[5] + red[6] + red[7];
    float mean = s1 * (1.0f / DMODEL);
    float var  = s2 * (1.0f / DMODEL) - mean * mean;
    float rs   = rsqrtf(var + 1e-5f);
    float4 gv = ((const float4*)g)[tid];
    float4 bv = ((const float4*)b)[tid];
    size_t o = (size_t)row * DMODEL + tid * 4;
    out[o + 0] = f2bf((v.x - mean) * rs * gv.x + bv.x);
    out[o + 1] = f2bf((v.y - mean) * rs * gv.y + bv.y);
    out[o + 2] = f2bf((v.z - mean) * rs * gv.z + bv.z);
    out[o + 3] = f2bf((v.w - mean) * rs * gv.w + bv.w);
}

// ---------------- fast transpose + fp32->bf16: W[K][N](ldW) -> WT[N][K] ----------------
__global__ __launch_bounds__(256) void transpose_bf16(const float* __restrict__ W,
                                                      unsigned short* __restrict__ WT,
                                                      int K, int ldW) {
    __shared__ float tile[64][65];
    int n0 = blockIdx.x * 64, k0 = blockIdx.y * 64;
    int tid = threadIdx.x;
    int lr4 = tid & 15;
    int rw  = tid >> 4;
#pragma unroll
    for (int p = 0; p < 4; ++p) {
        int k = rw + p * 16;
        float4 v = *(const float4*)(W + (size_t)(k0 + k) * ldW + n0 + lr4 * 4);
        tile[k][lr4 * 4 + 0] = v.x;
        tile[k][lr4 * 4 + 1] = v.y;
        tile[k][lr4 * 4 + 2] = v.z;
        tile[k][lr4 * 4 + 3] = v.w;
    }
    __syncthreads();
    int kc = tid & 15;
    int nr = tid >> 4;
#pragma unroll
    for (int p = 0; p < 4; ++p) {
        int n = nr + p * 16;
        ushort4 o;
        o.x = f2bf(tile[kc * 4 + 0][n]);
        o.y = f2bf(tile[kc * 4 + 1][n]);
        o.z = f2bf(tile[kc * 4 + 2][n]);
        o.w = f2bf(tile[kc * 4 + 3][n]);
        *(ushort4*)(WT + (size_t)(n0 + n) * K + k0 + kc * 4) = o;
    }
}

// fused QKV transpose: z selects Wq/Wk/Wv, writes into 3-stacked WT
__global__ __launch_bounds__(256) void transpose_qkv(const float* __restrict__ Wq,
                                                     const float* __restrict__ Wk,
                                                     const float* __restrict__ Wv,
                                                     unsigned short* __restrict__ WT) {
    __shared__ float tile[64][65];
    const float* W = (blockIdx.z == 0) ? Wq : (blockIdx.z == 1) ? Wk : Wv;
    unsigned short* dst = WT + (size_t)blockIdx.z * DMODEL * DMODEL;
    int n0 = blockIdx.x * 64, k0 = blockIdx.y * 64;
    int tid = threadIdx.x;
    int lr4 = tid & 15, rw = tid >> 4;
#pragma unroll
    for (int p = 0; p < 4; ++p) {
        int k = rw + p * 16;
        float4 v = *(const float4*)(W + (size_t)(k0 + k) * DMODEL + n0 + lr4 * 4);
        tile[k][lr4 * 4 + 0] = v.x;
        tile[k][lr4 * 4 + 1] = v.y;
        tile[k][lr4 * 4 + 2] = v.z;
        tile[k][lr4 * 4 + 3] = v.w;
    }
    __syncthreads();
    int kc = tid & 15, nr = tid >> 4;
#pragma unroll
    for (int p = 0; p < 4; ++p) {
        int n = nr + p * 16;
        ushort4 o;
        o.x = f2bf(tile[kc * 4 + 0][n]);
        o.y = f2bf(tile[kc * 4 + 1][n]);
        o.z = f2bf(tile[kc * 4 + 2][n]);
        o.w = f2bf(tile[kc * 4 + 3][n]);
        *(ushort4*)(dst + (size_t)(n0 + n) * DMODEL + k0 + kc * 4) = o;
    }
}

// ---------------- pack fused QKV bias for all layers ----------------
__global__ __launch_bounds__(256) void pack_qkv_bias(const float* __restrict__ bq,
                                                     const float* __restrict__ bk,
                                                     const float* __restrict__ bv,
                                                     float* __restrict__ dst) {
    int i = blockIdx.x * 256 + threadIdx.x;
    int l = i / 3072, c = i % 3072;
    float v = (c < 1024) ? bq[l * 1024 + c]
            : (c < 2048) ? bk[l * 1024 + c - 1024]
                         : bv[l * 1024 + c - 2048];
    dst[i] = v;
}

// ---------------- split-K combine: x += p0 + p1 + bias ----------------
__global__ __launch_bounds__(256) void combine2(const float* __restrict__ p0,
                                                const float* __restrict__ p1,
                                                const float* __restrict__ bias,
                                                float* __restrict__ x) {
    int i = blockIdx.x * 256 + threadIdx.x;              // float4 index
    float4 a = ((const float4*)p0)[i];
    float4 b = ((const float4*)p1)[i];
    float4 xv = ((float4*)x)[i];
    int col = (i * 4) & (DMODEL - 1);
    float4 bb = *(const float4*)(bias + col);
    xv.x += a.x + b.x + bb.x;
    xv.y += a.y + b.y + bb.y;
    xv.z += a.z + b.z + bb.z;
    xv.w += a.w + b.w + bb.w;
    ((float4*)x)[i] = xv;
}

// ---------------- band attention (width-3), bf16 qkv in ----------------
__global__ __launch_bounds__(256) void attn_kernel(const unsigned short* __restrict__ qkv,
                                                   unsigned short* __restrict__ y) {
    int wid  = (blockIdx.x * 256 + threadIdx.x) >> 6;
    int lane = threadIdx.x & 63;
    int h = wid & (NHEAD - 1);
    int row = wid >> 4;
    int t = row & (TSEQ - 1);
    const unsigned short* base = qkv + (size_t)row * 3072 + h * 64;
    float qd = bf2f(base[lane]);
    float d0 = qd * bf2f(base[1024 + lane]);
    float d1 = (t >= 1) ? qd * bf2f(base[1024 - 3072 + lane]) : 0.0f;
    float d2 = (t >= 2) ? qd * bf2f(base[1024 - 6144 + lane]) : 0.0f;
    for (int s = 32; s; s >>= 1) {
        d0 += __shfl_xor(d0, s); d1 += __shfl_xor(d1, s); d2 += __shfl_xor(d2, s);
    }
    d0 *= 0.125f; d1 *= 0.125f; d2 *= 0.125f;
    float m = d0;
    if (t >= 1) m = fmaxf(m, d1);
    if (t >= 2) m = fmaxf(m, d2);
    float p0 = expf(d0 - m);
    float p1 = (t >= 1) ? expf(d1 - m) : 0.0f;
    float p2 = (t >= 2) ? expf(d2 - m) : 0.0f;
    float den = p0 + p1 + p2;
    float v0 = bf2f(base[2048 + lane]);
    float v1 = (t >= 1) ? bf2f(base[2048 - 3072 + lane]) : 0.0f;
    float v2 = (t >= 2) ? bf2f(base[2048 - 6144 + lane]) : 0.0f;
    float yv = (p0 * v0 + p1 * v1 + p2 * v2) / den;
    y[(size_t)row * DMODEL + h * 64 + lane] = f2bf(yv);
}

// ======================================================================
// gemmv2: 128x128 tile, 256 threads / 4 waves (wave tile 64x64), BK=32,
// 2 LDS buffers (32 KB) -> 3 blocks/CU (m97/m114 TLP mechanism).
// Packed-line zero-conflict LDS layout.  Split-K via blockIdx.y.
// EPI: 0=raw f32 partial, 1=bias+res->f32, 2=gelu(bias)->bf16, 3=bias->bf16
// ======================================================================
template <int EPI>
__global__ __launch_bounds__(256, 3) void gemmv2(const unsigned short* __restrict__ A,
                                                 const unsigned short* __restrict__ BT,
                                                 const float* __restrict__ bias,
                                                 const float* __restrict__ res,
                                                 float* __restrict__ outF,
                                                 unsigned short* __restrict__ outB,
                                                 int M, int N, int Ks, int KL, int ldc) {
    __shared__ unsigned short As[2][4096];
    __shared__ unsigned short Bs[2][4096];
    const int tid = threadIdx.x;
    const int lane = tid & 63, wid = tid >> 6;
    const int wr = wid >> 1, wc = wid & 1;       // 2x2 waves, wave tile 64x64
    const int lr = lane & 15, kq = lane >> 4;

    const int nbm = M >> 7;
    const int nwg = gridDim.x;
    int orig = blockIdx.x;
    int q8 = nwg >> 3, r8 = nwg & 7;
    int xcd = orig & 7, lin = orig >> 3;
    int wg = (xcd < r8 ? xcd * (q8 + 1) : r8 * (q8 + 1) + (xcd - r8) * q8) + lin;
    int bm = wg % nbm, bn = wg / nbm;
    const int kc = blockIdx.y;

    const unsigned short* Ab = A + (size_t)bm * 128 * Ks + (size_t)kc * KL;
    const unsigned short* Bb = BT + (size_t)bn * 128 * Ks + (size_t)kc * KL;

    int sOff[2];
#pragma unroll
    for (int i = 0; i < 2; ++i) {
        int pc = i * 256 + tid;
        int line = pc >> 3, slot = pc & 7;
        int row = line * 2 + (slot >> 2);
        int c = (slot & 3) ^ (line & 3);
        sOff[i] = row * Ks + c * 8;
    }

#define STAGEV2(T) do {                                                                        \
    unsigned short* dA_ = &As[(T) & 1][0];                                                     \
    unsigned short* dB_ = &Bs[(T) & 1][0];                                                     \
    _Pragma("unroll") for (int i_ = 0; i_ < 2; ++i_) {                                         \
        __builtin_amdgcn_global_load_lds(                                                      \
            (const __attribute__((address_space(1))) void*)(Ab + sOff[i_] + (T) * 32),         \
            (__attribute__((address_space(3))) void*)(dA_ + (size_t)(i_ * 256 + tid) * 8), 16, 0, 0); \
        __builtin_amdgcn_global_load_lds(                                                      \
            (const __attribute__((address_space(1))) void*)(Bb + sOff[i_] + (T) * 32),         \
            (__attribute__((address_space(3))) void*)(dB_ + (size_t)(i_ * 256 + tid) * 8), 16, 0, 0); \
    }                                                                                          \
} while (0)

    const int slot = ((lane & 1) << 2) | (kq ^ ((lr >> 1) & 3));
    const int laneOff = ((lr >> 1) << 6) + slot * 8;
    int aOff[4], bOff[4];
#pragma unroll
    for (int m = 0; m < 4; ++m) aOff[m] = wr * 2048 + m * 512 + laneOff;
#pragma unroll
    for (int n = 0; n < 4; ++n) bOff[n] = wc * 2048 + n * 512 + laneOff;

    f32x4 acc[4][4] = {};
    const int nt = KL >> 5;

    STAGEV2(0);
    __syncthreads();

    for (int t = 0; t < nt; ++t) {
        const bool pf = (t + 1) < nt;
        if (pf) STAGEV2(t + 1);
        const unsigned short* sA = &As[t & 1][0];
        const unsigned short* sB = &Bs[t & 1][0];
        bf16x8 a[4], b[4];
#pragma unroll
        for (int m = 0; m < 4; ++m) a[m] = *(const bf16x8*)(sA + aOff[m]);
#pragma unroll
        for (int n = 0; n < 4; ++n) b[n] = *(const bf16x8*)(sB + bOff[n]);
        __builtin_amdgcn_s_setprio(1);
#pragma unroll
        for (int m = 0; m < 4; ++m)
#pragma unroll
            for (int n = 0; n < 4; ++n)
                acc[m][n] = __builtin_amdgcn_mfma_f32_16x16x32_bf16(a[m], b[n], acc[m][n], 0, 0, 0);
        __builtin_amdgcn_s_setprio(0);
        if (pf) __syncthreads();
    }

    const int row0 = bm * 128 + wr * 64;
    const int col0 = bn * 128 + wc * 64;
    float* outP = (EPI == 0) ? (outF + (size_t)kc * M * ldc) : outF;
#pragma unroll
    for (int m = 0; m < 4; ++m) {
#pragma unroll
        for (int n = 0; n < 4; ++n) {
            int col = col0 + n * 16 + lr;
            int rbase = row0 + m * 16 + kq * 4;
            float bb = (EPI != 0 && bias) ? bias[col] : 0.0f;
#pragma unroll
            for (int j = 0; j < 4; ++j) {
                size_t off = (size_t)(rbase + j) * ldc + col;
                float v = acc[m][n][j] + bb;
                if (EPI == 1) v += res[off];
                if (EPI == 2)      outB[off] = f2bf(gelu_exact(v));
                else if (EPI == 3) outB[off] = f2bf(v);
                else               outP[off] = v;
            }
        }
    }
#undef STAGEV2
}

// ======================================================================
// gemm256v3: 256x256 tile, BK=32, DOUBLE-buffered 64 KB LDS -> 2 blocks/CU
// (cross-block TLP). Simple m97-style loop: stage(t+1) -> frag reads ->
// 32 MFMA -> __syncthreads.  Packed-line zero-conflict layout, bn-major
// XCD-swizzled block order.  EPI0 only (LM head, f32 out).
// ======================================================================
__global__ __launch_bounds__(512, 4) void gemm256v3(const unsigned short* __restrict__ A,
                                                    const unsigned short* __restrict__ BT,
                                                    float* __restrict__ outF,
                                                    int M, int N, int K, int ldc) {
    __shared__ unsigned short As[2][8192];
    __shared__ unsigned short Bs[2][8192];
    const int tid = threadIdx.x;
    const int lane = tid & 63, wid = tid >> 6;
    const int wr = wid >> 2, wc = wid & 3;       // 2x4 waves; wave tile 128x64
    const int lr = lane & 15, kq = lane >> 4;

    const int nbm = M >> 8;
    const int nwg = gridDim.x;
    int orig = blockIdx.x;
    int q8 = nwg >> 3, r8 = nwg & 7;
    int xcd = orig & 7, lin = orig >> 3;
    int wg = (xcd < r8 ? xcd * (q8 + 1) : r8 * (q8 + 1) + (xcd - r8) * q8) + lin;
    int bm = wg % nbm, bn = wg / nbm;

    const unsigned short* Ab = A + (size_t)bm * 256 * K;
    const unsigned short* Bb = BT + (size_t)bn * 256 * K;

    // staging: 1024 16B-chunks per operand per tile; 2 per thread per operand
    int sOff[2];
#pragma unroll
    for (int i = 0; i < 2; ++i) {
        int pc = i * 512 + tid;
        int line = pc >> 3, slot = pc & 7;
        int row = line * 2 + (slot >> 2);
        int c = (slot & 3) ^ (line & 3);
        sOff[i] = row * K + c * 8;
    }

#define STAGEV3(T) do {                                                                        \
    unsigned short* dA_ = &As[(T) & 1][0];                                                     \
    unsigned short* dB_ = &Bs[(T) & 1][0];                                                     \
    _Pragma("unroll") for (int i_ = 0; i_ < 2; ++i_) {                                         \
        __builtin_amdgcn_global_load_lds(                                                      \
            (const __attribute__((address_space(1))) void*)(Ab + sOff[i_] + (T) * 32),         \
            (__attribute__((address_space(3))) void*)(dA_ + (size_t)(i_ * 512 + tid) * 8), 16, 0, 0); \
        __builtin_amdgcn_global_load_lds(                                                      \
            (const __attribute__((address_space(1))) void*)(Bb + sOff[i_] + (T) * 32),         \
            (__attribute__((address_space(3))) void*)(dB_ + (size_t)(i_ * 512 + tid) * 8), 16, 0, 0); \
    }                                                                                          \
} while (0)

    const int slot = ((lane & 1) << 2) | (kq ^ ((lr >> 1) & 3));
    const int laneOff = ((lr >> 1) << 6) + slot * 8;
    int aOff[8], bOff[4];
#pragma unroll
    for (int m = 0; m < 8; ++m) aOff[m] = wr * 4096 + m * 512 + laneOff;
#pragma unroll
    for (int n = 0; n < 4; ++n) bOff[n] = wc * 2048 + n * 512 + laneOff;

    f32x4 acc[8][4] = {};
    const int nt = K >> 5;

    STAGEV3(0);
    __syncthreads();

    for (int t = 0; t < nt; ++t) {
        const bool pf = (t + 1) < nt;
        if (pf) STAGEV3(t + 1);
        const unsigned short* sA = &As[t & 1][0];
        const unsigned short* sB = &Bs[t & 1][0];
        bf16x8 a[8], b[4];
#pragma unroll
        for (int m = 0; m < 8; ++m) a[m] = *(const bf16x8*)(sA + aOff[m]);
#pragma unroll
        for (int n = 0; n < 4; ++n) b[n] = *(const bf16x8*)(sB + bOff[n]);
        __builtin_amdgcn_s_setprio(1);
#pragma unroll
        for (int m = 0; m < 8; ++m)
#pragma unroll
            for (int n = 0; n < 4; ++n)
                acc[m][n] = __builtin_amdgcn_mfma_f32_16x16x32_bf16(a[m], b[n], acc[m][n], 0, 0, 0);
        __builtin_amdgcn_s_setprio(0);
        if (pf) __syncthreads();
    }

    const int row0 = bm * 256 + wr * 128;
    const int col0 = bn * 256 + wc * 64;
#pragma unroll
    for (int m = 0; m < 8; ++m) {
#pragma unroll
        for (int n = 0; n < 4; ++n) {
            int col = col0 + n * 16 + lr;
            int rbase = row0 + m * 16 + kq * 4;
#pragma unroll
            for (int j = 0; j < 4; ++j) {
                size_t off = (size_t)(rbase + j) * ldc + col;
                outF[off] = acc[m][n][j];
            }
        }
    }
#undef STAGEV3
}

// ---------------- host launch ----------------
extern "C" void kernel_launch(void* const* d_in, const int* in_sizes, int n_in,
                              void* d_out, int out_size, void* d_ws, size_t ws_size,
                              hipStream_t stream) {
    const int*   idx  = (const int*)d_in[0];
    const float* tok  = (const float*)d_in[1];
    const float* pos  = (const float*)d_in[2];
    const float* Wq   = (const float*)d_in[3];
    const float* bq   = (const float*)d_in[4];
    const float* Wk   = (const float*)d_in[5];
    const float* bk   = (const float*)d_in[6];
    const float* Wv   = (const float*)d_in[7];
    const float* bv   = (const float*)d_in[8];
    const float* Wo   = (const float*)d_in[9];
    const float* bo   = (const float*)d_in[10];
    const float* ln1g = (const float*)d_in[11];
    const float* ln1b = (const float*)d_in[12];
    const float* W1   = (const float*)d_in[13];
    const float* b1   = (const float*)d_in[14];
    const float* W2   = (const float*)d_in[15];
    const float* b2   = (const float*)d_in[16];
    const float* ln2g = (const float*)d_in[17];
    const float* ln2b = (const float*)d_in[18];
    const float* lnfg = (const float*)d_in[19];
    const float* lnfb = (const float*)d_in[20];
    const float* lmW  = (const float*)d_in[21];

    const bool bigws = ws_size >= (92ull << 20);

    char* ws = (char*)d_ws;
    unsigned short* wbuf;
    unsigned short* hbuf;
    unsigned short* ybuf;
    unsigned short* xfbuf;
    float*          bqkv;
    if (bigws) {
        wbuf  = (unsigned short*)(ws);
        hbuf  = (unsigned short*)(ws + (63ull << 20));
        ybuf  = (unsigned short*)(ws + (71ull << 20));
        xfbuf = (unsigned short*)(ws + (79ull << 20));
        bqkv  = (float*)(ws + (87ull << 20));
    } else {
        wbuf  = (unsigned short*)(ws);
        hbuf  = (unsigned short*)(ws + (16u << 20));
        ybuf  = (unsigned short*)(ws + (24u << 20));
        xfbuf = (unsigned short*)(ws + (32u << 20));
        bqkv  = (float*)(ws + (40u << 20));
    }

    // scratch inside d_out (dead before LM-head GEMM overwrites all of d_out)
    float* outF = (float*)d_out;
    float* xbuf = outF;                                                        // [0,16) MiB residual fp32
    unsigned short* qkv = (unsigned short*)((char*)d_out + (16ull << 20));     // [16,40) MiB bf16 qkv
    unsigned short* hidden = (unsigned short*)((char*)d_out + (64ull << 20));  // [64,96) MiB bf16 hidden
    float* pbuf = (float*)((char*)d_out + (96ull << 20));                      // [96,128) MiB split-K partials

    embed_kernel<<<MROWS, 256, 0, stream>>>(idx, tok, pos, xbuf);
    pack_qkv_bias<<<(NLAYER * 3072) / 256, 256, 0, stream>>>(bq, bk, bv, bqkv);

    for (int l = 0; l < NLAYER; l++) {
        const size_t wl = (size_t)l * DMODEL * DMODEL;
        ln_kernel<<<MROWS, 256, 0, stream>>>(xbuf, ln1g + l * DMODEL, ln1b + l * DMODEL, hbuf);

        // QKV: gemmv2 EPI3 (grid 768 = 3 blocks/CU exactly)
        transpose_qkv<<<dim3(16, 16, 3), 256, 0, stream>>>(Wq + wl, Wk + wl, Wv + wl, wbuf);
        gemmv2<3><<<dim3((MROWS / 128) * (3072 / 128), 1), 256, 0, stream>>>(
            hbuf, wbuf, bqkv + l * 3072, nullptr, nullptr, qkv, MROWS, 3072, DMODEL, DMODEL, 3072);

        attn_kernel<<<MROWS * NHEAD / 4, 256, 0, stream>>>(qkv, ybuf);

        // Wo: gemmv2 fused bias+res
        transpose_bf16<<<dim3(16, 16), 256, 0, stream>>>(Wo + wl, wbuf, DMODEL, DMODEL);
        gemmv2<1><<<dim3((MROWS / 128) * (DMODEL / 128), 1), 256, 0, stream>>>(
            ybuf, wbuf, bo + l * DMODEL, xbuf, xbuf, nullptr, MROWS, DMODEL, DMODEL, DMODEL, DMODEL);

        ln_kernel<<<MROWS, 256, 0, stream>>>(xbuf, ln2g + l * DMODEL, ln2b + l * DMODEL, hbuf);

        // W1: gemmv2 gelu
        transpose_bf16<<<dim3(FFN / 64, DMODEL / 64), 256, 0, stream>>>(W1 + (size_t)l * DMODEL * FFN, wbuf, DMODEL, FFN);
        gemmv2<2><<<dim3((MROWS / 128) * (FFN / 128), 1), 256, 0, stream>>>(
            hbuf, wbuf, b1 + l * FFN, nullptr, nullptr, hidden, MROWS, FFN, DMODEL, DMODEL, FFN);

        // W2: gemmv2 split-K=2 + combine
        transpose_bf16<<<dim3(DMODEL / 64, FFN / 64), 256, 0, stream>>>(W2 + (size_t)l * FFN * DMODEL, wbuf, FFN, DMODEL);
        gemmv2<0><<<dim3((MROWS / 128) * (DMODEL / 128), 2), 256, 0, stream>>>(
            hidden, wbuf, nullptr, nullptr, pbuf, nullptr, MROWS, DMODEL, FFN, FFN / 2, DMODEL);
        combine2<<<MROWS * DMODEL / 4 / 256, 256, 0, stream>>>(
            pbuf, pbuf + (size_t)MROWS * DMODEL, b2 + l * DMODEL, xbuf);
    }

    ln_kernel<<<MROWS, 256, 0, stream>>>(xbuf, lnfg, lnfb, xfbuf);

    if (bigws) {
        transpose_bf16<<<dim3(NVOCAB / 64, DMODEL / 64), 256, 0, stream>>>(lmW, wbuf, DMODEL, NVOCAB);
        gemm256v3<<<dim3((NVOCAB / 256) * (MROWS / 256)), 512, 0, stream>>>(
            xfbuf, wbuf, outF, MROWS, NVOCAB, DMODEL, NVOCAB);
    } else {
        const int NCHUNK = 6400;
        for (int c = 0; c < NVOCAB / NCHUNK; c++) {
            int n0 = c * NCHUNK;
            transpose_bf16<<<dim3(NCHUNK / 64, DMODEL / 64), 256, 0, stream>>>(lmW + n0, wbuf, DMODEL, NVOCAB);
            gemm256v3<<<dim3((NCHUNK / 256) * (MROWS / 256)), 512, 0, stream>>>(
                xfbuf, wbuf, outF + n0, MROWS, NCHUNK, DMODEL, NVOCAB);
        }
    }
}

// Round 12
// 1373.526 us; speedup vs baseline: 2.5898x; 2.5898x over previous
//
#include <hip/hip_runtime.h>
#include <cstdint>
#include <cstddef>

// ---------------- constants ----------------
#define MROWS   4096      // B*T
#define TSEQ    2048
#define DMODEL  1024
#define NHEAD   16
#define FFN     4096
#define NVOCAB  32000
#define NLAYER  4

typedef float  f32x4  __attribute__((ext_vector_type(4)));
typedef __bf16 bf16x8 __attribute__((ext_vector_type(8)));

__device__ __forceinline__ unsigned short f2bf(float f) {
    unsigned u = __builtin_bit_cast(unsigned, f);
    u += 0x7fffu + ((u >> 16) & 1u);
    return (unsigned short)(u >> 16);
}
__device__ __forceinline__ float bf2f(unsigned short u) {
    return __builtin_bit_cast(float, (unsigned)u << 16);
}

__device__ __forceinline__ float gelu_exact(float v) {
    return 0.5f * v * (1.0f + erff(v * 0.7071067811865476f));
}

// ---------------- embedding ----------------
__global__ __launch_bounds__(256) void embed_kernel(const int* __restrict__ idx,
                                                    const float* __restrict__ tok,
                                                    const float* __restrict__ pos,
                                                    float* __restrict__ x) {
    int row = blockIdx.x, tid = threadIdx.x;
    int token = idx[row];
    int t = row & (TSEQ - 1);
    float4 a = ((const float4*)(tok + (size_t)token * DMODEL))[tid];
    float4 p = ((const float4*)(pos + (size_t)t * DMODEL))[tid];
    a.x += p.x; a.y += p.y; a.z += p.z; a.w += p.w;
    ((float4*)(x + (size_t)row * DMODEL))[tid] = a;
}

// ---------------- LayerNorm fp32 in -> bf16 out ----------------
__global__ __launch_bounds__(256) void ln_kernel(const float* __restrict__ x,
                                                 const float* __restrict__ g,
                                                 const float* __restrict__ b,
                                                 unsigned short* __restrict__ out) {
    int row = blockIdx.x, tid = threadIdx.x;
    float4 v = ((const float4*)(x + (size_t)row * DMODEL))[tid];
    float s1 = v.x + v.y + v.z + v.w;
    float s2 = v.x * v.x + v.y * v.y + v.z * v.z + v.w * v.w;
    for (int s = 32; s; s >>= 1) { s1 += __shfl_xor(s1, s); s2 += __shfl_xor(s2, s); }
    __shared__ float red[8];
    int lane = tid & 63, w = tid >> 6;
    if (lane == 0) { red[w] = s1; red[4 + w] = s2; }
    __syncthreads();
    s1 = red[0] + red[1] + red[2] + red[3];
    s2 = red[4] + red[5] + red[6] + red[7];
    float mean = s1 * (1.0f / DMODEL);
    float var  = s2 * (1.0f / DMODEL) - mean * mean;
    float rs   = rsqrtf(var + 1e-5f);
    float4 gv = ((const float4*)g)[tid];
    float4 bv = ((const float4*)b)[tid];
    size_t o = (size_t)row * DMODEL + tid * 4;
    out[o + 0] = f2bf((v.x - mean) * rs * gv.x + bv.x);
    out[o + 1] = f2bf((v.y - mean) * rs * gv.y + bv.y);
    out[o + 2] = f2bf((v.z - mean) * rs * gv.z + bv.z);
    out[o + 3] = f2bf((v.w - mean) * rs * gv.w + bv.w);
}

// ---------------- fast transpose + fp32->bf16: W[K][N](ldW) -> WT[N][K] ----------------
__global__ __launch_bounds__(256) void transpose_bf16(const float* __restrict__ W,
                                                      unsigned short* __restrict__ WT,
                                                      int K, int ldW) {
    __shared__ float tile[64][65];
    int n0 = blockIdx.x * 64, k0 = blockIdx.y * 64;
    int tid = threadIdx.x;
    int lr4 = tid & 15;
    int rw  = tid >> 4;
#pragma unroll
    for (int p = 0; p < 4; ++p) {
        int k = rw + p * 16;
        float4 v = *(const float4*)(W + (size_t)(k0 + k) * ldW + n0 + lr4 * 4);
        tile[k][lr4 * 4 + 0] = v.x;
        tile[k][lr4 * 4 + 1] = v.y;
        tile[k][lr4 * 4 + 2] = v.z;
        tile[k][lr4 * 4 + 3] = v.w;
    }
    __syncthreads();
    int kc = tid & 15;
    int nr = tid >> 4;
#pragma unroll
    for (int p = 0; p < 4; ++p) {
        int n = nr + p * 16;
        ushort4 o;
        o.x = f2bf(tile[kc * 4 + 0][n]);
        o.y = f2bf(tile[kc * 4 + 1][n]);
        o.z = f2bf(tile[kc * 4 + 2][n]);
        o.w = f2bf(tile[kc * 4 + 3][n]);
        *(ushort4*)(WT + (size_t)(n0 + n) * K + k0 + kc * 4) = o;
    }
}

// fused QKV transpose: z selects Wq/Wk/Wv, writes into 3-stacked WT
__global__ __launch_bounds__(256) void transpose_qkv(const float* __restrict__ Wq,
                                                     const float* __restrict__ Wk,
                                                     const float* __restrict__ Wv,
                                                     unsigned short* __restrict__ WT) {
    __shared__ float tile[64][65];
    const float* W = (blockIdx.z == 0) ? Wq : (blockIdx.z == 1) ? Wk : Wv;
    unsigned short* dst = WT + (size_t)blockIdx.z * DMODEL * DMODEL;
    int n0 = blockIdx.x * 64, k0 = blockIdx.y * 64;
    int tid = threadIdx.x;
    int lr4 = tid & 15, rw = tid >> 4;
#pragma unroll
    for (int p = 0; p < 4; ++p) {
        int k = rw + p * 16;
        float4 v = *(const float4*)(W + (size_t)(k0 + k) * DMODEL + n0 + lr4 * 4);
        tile[k][lr4 * 4 + 0] = v.x;
        tile[k][lr4 * 4 + 1] = v.y;
        tile[k][lr4 * 4 + 2] = v.z;
        tile[k][lr4 * 4 + 3] = v.w;
    }
    __syncthreads();
    int kc = tid & 15, nr = tid >> 4;
#pragma unroll
    for (int p = 0; p < 4; ++p) {
        int n = nr + p * 16;
        ushort4 o;
        o.x = f2bf(tile[kc * 4 + 0][n]);
        o.y = f2bf(tile[kc * 4 + 1][n]);
        o.z = f2bf(tile[kc * 4 + 2][n]);
        o.w = f2bf(tile[kc * 4 + 3][n]);
        *(ushort4*)(dst + (size_t)(n0 + n) * DMODEL + k0 + kc * 4) = o;
    }
}

// ---------------- pack fused QKV bias for all layers ----------------
__global__ __launch_bounds__(256) void pack_qkv_bias(const float* __restrict__ bq,
                                                     const float* __restrict__ bk,
                                                     const float* __restrict__ bv,
                                                     float* __restrict__ dst) {
    int i = blockIdx.x * 256 + threadIdx.x;
    int l = i / 3072, c = i % 3072;
    float v = (c < 1024) ? bq[l * 1024 + c]
            : (c < 2048) ? bk[l * 1024 + c - 1024]
                         : bv[l * 1024 + c - 2048];
    dst[i] = v;
}

// ---------------- split-K combine: x += p0 + p1 + bias ----------------
__global__ __launch_bounds__(256) void combine2(const float* __restrict__ p0,
                                                const float* __restrict__ p1,
                                                const float* __restrict__ bias,
                                                float* __restrict__ x) {
    int i = blockIdx.x * 256 + threadIdx.x;              // float4 index
    float4 a = ((const float4*)p0)[i];
    float4 b = ((const float4*)p1)[i];
    float4 xv = ((float4*)x)[i];
    int col = (i * 4) & (DMODEL - 1);
    float4 bb = *(const float4*)(bias + col);
    xv.x += a.x + b.x + bb.x;
    xv.y += a.y + b.y + bb.y;
    xv.z += a.z + b.z + bb.z;
    xv.w += a.w + b.w + bb.w;
    ((float4*)x)[i] = xv;
}

// ---------------- band attention (width-3), bf16 qkv in ----------------
__global__ __launch_bounds__(256) void attn_kernel(const unsigned short* __restrict__ qkv,
                                                   unsigned short* __restrict__ y) {
    int wid  = (blockIdx.x * 256 + threadIdx.x) >> 6;
    int lane = threadIdx.x & 63;
    int h = wid & (NHEAD - 1);
    int row = wid >> 4;
    int t = row & (TSEQ - 1);
    const unsigned short* base = qkv + (size_t)row * 3072 + h * 64;
    float qd = bf2f(base[lane]);
    float d0 = qd * bf2f(base[1024 + lane]);
    float d1 = (t >= 1) ? qd * bf2f(base[1024 - 3072 + lane]) : 0.0f;
    float d2 = (t >= 2) ? qd * bf2f(base[1024 - 6144 + lane]) : 0.0f;
    for (int s = 32; s; s >>= 1) {
        d0 += __shfl_xor(d0, s); d1 += __shfl_xor(d1, s); d2 += __shfl_xor(d2, s);
    }
    d0 *= 0.125f; d1 *= 0.125f; d2 *= 0.125f;
    float m = d0;
    if (t >= 1) m = fmaxf(m, d1);
    if (t >= 2) m = fmaxf(m, d2);
    float p0 = expf(d0 - m);
    float p1 = (t >= 1) ? expf(d1 - m) : 0.0f;
    float p2 = (t >= 2) ? expf(d2 - m) : 0.0f;
    float den = p0 + p1 + p2;
    float v0 = bf2f(base[2048 + lane]);
    float v1 = (t >= 1) ? bf2f(base[2048 - 3072 + lane]) : 0.0f;
    float v2 = (t >= 2) ? bf2f(base[2048 - 6144 + lane]) : 0.0f;
    float yv = (p0 * v0 + p1 * v1 + p2 * v2) / den;
    y[(size_t)row * DMODEL + h * 64 + lane] = f2bf(yv);
}

// ======================================================================
// gemmv2: 128x128 tile, 256 threads / 4 waves (wave tile 64x64), BK=32,
// 2 LDS buffers (32 KB) -> 3 blocks/CU (m97/m114 TLP mechanism).
// Packed-line zero-conflict LDS layout.  Split-K via blockIdx.y.
// EPI: 0=raw f32 partial, 1=bias+res->f32, 2=gelu(bias)->bf16, 3=bias->bf16
// NOTE (R11 lesson): do NOT raise min-waves/EU here — acc needs ~130 VGPR;
// (256,3) keeps the allocator at <=170 and delivers 3 blocks/CU.
// ======================================================================
template <int EPI>
__global__ __launch_bounds__(256, 3) void gemmv2(const unsigned short* __restrict__ A,
                                                 const unsigned short* __restrict__ BT,
                                                 const float* __restrict__ bias,
                                                 const float* __restrict__ res,
                                                 float* __restrict__ outF,
                                                 unsigned short* __restrict__ outB,
                                                 int M, int N, int Ks, int KL, int ldc) {
    __shared__ unsigned short As[2][4096];
    __shared__ unsigned short Bs[2][4096];
    const int tid = threadIdx.x;
    const int lane = tid & 63, wid = tid >> 6;
    const int wr = wid >> 1, wc = wid & 1;       // 2x2 waves, wave tile 64x64
    const int lr = lane & 15, kq = lane >> 4;

    const int nbm = M >> 7;
    const int nwg = gridDim.x;
    int orig = blockIdx.x;
    int q8 = nwg >> 3, r8 = nwg & 7;
    int xcd = orig & 7, lin = orig >> 3;
    int wg = (xcd < r8 ? xcd * (q8 + 1) : r8 * (q8 + 1) + (xcd - r8) * q8) + lin;
    int bm = wg % nbm, bn = wg / nbm;
    const int kc = blockIdx.y;

    const unsigned short* Ab = A + (size_t)bm * 128 * Ks + (size_t)kc * KL;
    const unsigned short* Bb = BT + (size_t)bn * 128 * Ks + (size_t)kc * KL;

    int sOff[2];
#pragma unroll
    for (int i = 0; i < 2; ++i) {
        int pc = i * 256 + tid;
        int line = pc >> 3, slot = pc & 7;
        int row = line * 2 + (slot >> 2);
        int c = (slot & 3) ^ (line & 3);
        sOff[i] = row * Ks + c * 8;
    }

#define STAGEV2(T) do {                                                                        \
    unsigned short* dA_ = &As[(T) & 1][0];                                                     \
    unsigned short* dB_ = &Bs[(T) & 1][0];                                                     \
    _Pragma("unroll") for (int i_ = 0; i_ < 2; ++i_) {                                         \
        __builtin_amdgcn_global_load_lds(                                                      \
            (const __attribute__((address_space(1))) void*)(Ab + sOff[i_] + (T) * 32),         \
            (__attribute__((address_space(3))) void*)(dA_ + (size_t)(i_ * 256 + tid) * 8), 16, 0, 0); \
        __builtin_amdgcn_global_load_lds(                                                      \
            (const __attribute__((address_space(1))) void*)(Bb + sOff[i_] + (T) * 32),         \
            (__attribute__((address_space(3))) void*)(dB_ + (size_t)(i_ * 256 + tid) * 8), 16, 0, 0); \
    }                                                                                          \
} while (0)

    const int slot = ((lane & 1) << 2) | (kq ^ ((lr >> 1) & 3));
    const int laneOff = ((lr >> 1) << 6) + slot * 8;
    int aOff[4], bOff[4];
#pragma unroll
    for (int m = 0; m < 4; ++m) aOff[m] = wr * 2048 + m * 512 + laneOff;
#pragma unroll
    for (int n = 0; n < 4; ++n) bOff[n] = wc * 2048 + n * 512 + laneOff;

    f32x4 acc[4][4] = {};
    const int nt = KL >> 5;

    STAGEV2(0);
    __syncthreads();

    for (int t = 0; t < nt; ++t) {
        const bool pf = (t + 1) < nt;
        if (pf) STAGEV2(t + 1);
        const unsigned short* sA = &As[t & 1][0];
        const unsigned short* sB = &Bs[t & 1][0];
        bf16x8 a[4], b[4];
#pragma unroll
        for (int m = 0; m < 4; ++m) a[m] = *(const bf16x8*)(sA + aOff[m]);
#pragma unroll
        for (int n = 0; n < 4; ++n) b[n] = *(const bf16x8*)(sB + bOff[n]);
        __builtin_amdgcn_s_setprio(1);
#pragma unroll
        for (int m = 0; m < 4; ++m)
#pragma unroll
            for (int n = 0; n < 4; ++n)
                acc[m][n] = __builtin_amdgcn_mfma_f32_16x16x32_bf16(a[m], b[n], acc[m][n], 0, 0, 0);
        __builtin_amdgcn_s_setprio(0);
        if (pf) __syncthreads();
    }

    const int row0 = bm * 128 + wr * 64;
    const int col0 = bn * 128 + wc * 64;
    float* outP = (EPI == 0) ? (outF + (size_t)kc * M * ldc) : outF;
#pragma unroll
    for (int m = 0; m < 4; ++m) {
#pragma unroll
        for (int n = 0; n < 4; ++n) {
            int col = col0 + n * 16 + lr;
            int rbase = row0 + m * 16 + kq * 4;
            float bb = (EPI != 0 && bias) ? bias[col] : 0.0f;
#pragma unroll
            for (int j = 0; j < 4; ++j) {
                size_t off = (size_t)(rbase + j) * ldc + col;
                float v = acc[m][n][j] + bb;
                if (EPI == 1) v += res[off];
                if (EPI == 2)      outB[off] = f2bf(gelu_exact(v));
                else if (EPI == 3) outB[off] = f2bf(v);
                else               outP[off] = v;
            }
        }
    }
#undef STAGEV2
}

// ---------------- host launch ----------------
extern "C" void kernel_launch(void* const* d_in, const int* in_sizes, int n_in,
                              void* d_out, int out_size, void* d_ws, size_t ws_size,
                              hipStream_t stream) {
    const int*   idx  = (const int*)d_in[0];
    const float* tok  = (const float*)d_in[1];
    const float* pos  = (const float*)d_in[2];
    const float* Wq   = (const float*)d_in[3];
    const float* bq   = (const float*)d_in[4];
    const float* Wk   = (const float*)d_in[5];
    const float* bk   = (const float*)d_in[6];
    const float* Wv   = (const float*)d_in[7];
    const float* bv   = (const float*)d_in[8];
    const float* Wo   = (const float*)d_in[9];
    const float* bo   = (const float*)d_in[10];
    const float* ln1g = (const float*)d_in[11];
    const float* ln1b = (const float*)d_in[12];
    const float* W1   = (const float*)d_in[13];
    const float* b1   = (const float*)d_in[14];
    const float* W2   = (const float*)d_in[15];
    const float* b2   = (const float*)d_in[16];
    const float* ln2g = (const float*)d_in[17];
    const float* ln2b = (const float*)d_in[18];
    const float* lnfg = (const float*)d_in[19];
    const float* lnfb = (const float*)d_in[20];
    const float* lmW  = (const float*)d_in[21];

    const bool bigws = ws_size >= (92ull << 20);

    char* ws = (char*)d_ws;
    unsigned short* wbuf;
    unsigned short* hbuf;
    unsigned short* ybuf;
    unsigned short* xfbuf;
    float*          bqkv;
    if (bigws) {
        wbuf  = (unsigned short*)(ws);
        hbuf  = (unsigned short*)(ws + (63ull << 20));
        ybuf  = (unsigned short*)(ws + (71ull << 20));
        xfbuf = (unsigned short*)(ws + (79ull << 20));
        bqkv  = (float*)(ws + (87ull << 20));
    } else {
        wbuf  = (unsigned short*)(ws);
        hbuf  = (unsigned short*)(ws + (16u << 20));
        ybuf  = (unsigned short*)(ws + (24u << 20));
        xfbuf = (unsigned short*)(ws + (32u << 20));
        bqkv  = (float*)(ws + (40u << 20));
    }

    // scratch inside d_out (dead before LM-head GEMM overwrites all of d_out)
    float* outF = (float*)d_out;
    float* xbuf = outF;                                                        // [0,16) MiB residual fp32
    unsigned short* qkv = (unsigned short*)((char*)d_out + (16ull << 20));     // [16,40) MiB bf16 qkv
    unsigned short* hidden = (unsigned short*)((char*)d_out + (64ull << 20));  // [64,96) MiB bf16 hidden
    float* pbuf = (float*)((char*)d_out + (96ull << 20));                      // [96,128) MiB split-K partials

    embed_kernel<<<MROWS, 256, 0, stream>>>(idx, tok, pos, xbuf);
    pack_qkv_bias<<<(NLAYER * 3072) / 256, 256, 0, stream>>>(bq, bk, bv, bqkv);

    for (int l = 0; l < NLAYER; l++) {
        const size_t wl = (size_t)l * DMODEL * DMODEL;
        ln_kernel<<<MROWS, 256, 0, stream>>>(xbuf, ln1g + l * DMODEL, ln1b + l * DMODEL, hbuf);

        // QKV: gemmv2 EPI3 (grid 768 = 3 blocks/CU exactly)
        transpose_qkv<<<dim3(16, 16, 3), 256, 0, stream>>>(Wq + wl, Wk + wl, Wv + wl, wbuf);
        gemmv2<3><<<dim3((MROWS / 128) * (3072 / 128), 1), 256, 0, stream>>>(
            hbuf, wbuf, bqkv + l * 3072, nullptr, nullptr, qkv, MROWS, 3072, DMODEL, DMODEL, 3072);

        attn_kernel<<<MROWS * NHEAD / 4, 256, 0, stream>>>(qkv, ybuf);

        // Wo: gemmv2 fused bias+res
        transpose_bf16<<<dim3(16, 16), 256, 0, stream>>>(Wo + wl, wbuf, DMODEL, DMODEL);
        gemmv2<1><<<dim3((MROWS / 128) * (DMODEL / 128), 1), 256, 0, stream>>>(
            ybuf, wbuf, bo + l * DMODEL, xbuf, xbuf, nullptr, MROWS, DMODEL, DMODEL, DMODEL, DMODEL);

        ln_kernel<<<MROWS, 256, 0, stream>>>(xbuf, ln2g + l * DMODEL, ln2b + l * DMODEL, hbuf);

        // W1: gemmv2 gelu
        transpose_bf16<<<dim3(FFN / 64, DMODEL / 64), 256, 0, stream>>>(W1 + (size_t)l * DMODEL * FFN, wbuf, DMODEL, FFN);
        gemmv2<2><<<dim3((MROWS / 128) * (FFN / 128), 1), 256, 0, stream>>>(
            hbuf, wbuf, b1 + l * FFN, nullptr, nullptr, hidden, MROWS, FFN, DMODEL, DMODEL, FFN);

        // W2: gemmv2 split-K=2 + combine
        transpose_bf16<<<dim3(DMODEL / 64, FFN / 64), 256, 0, stream>>>(W2 + (size_t)l * FFN * DMODEL, wbuf, FFN, DMODEL);
        gemmv2<0><<<dim3((MROWS / 128) * (DMODEL / 128), 2), 256, 0, stream>>>(
            hidden, wbuf, nullptr, nullptr, pbuf, nullptr, MROWS, DMODEL, FFN, FFN / 2, DMODEL);
        combine2<<<MROWS * DMODEL / 4 / 256, 256, 0, stream>>>(
            pbuf, pbuf + (size_t)MROWS * DMODEL, b2 + l * DMODEL, xbuf);
    }

    ln_kernel<<<MROWS, 256, 0, stream>>>(xbuf, lnfg, lnfb, xfbuf);

    if (bigws) {
        // LM head: gemmv2 (3 blocks/CU TLP test), grid 32x250 = 8000 blocks
        transpose_bf16<<<dim3(NVOCAB / 64, DMODEL / 64), 256, 0, stream>>>(lmW, wbuf, DMODEL, NVOCAB);
        gemmv2<0><<<dim3((MROWS / 128) * (NVOCAB / 128), 1), 256, 0, stream>>>(
            xfbuf, wbuf, nullptr, nullptr, outF, nullptr, MROWS, NVOCAB, DMODEL, DMODEL, NVOCAB);
    } else {
        const int NCHUNK = 6400;
        for (int c = 0; c < NVOCAB / NCHUNK; c++) {
            int n0 = c * NCHUNK;
            transpose_bf16<<<dim3(NCHUNK / 64, DMODEL / 64), 256, 0, stream>>>(lmW + n0, wbuf, DMODEL, NVOCAB);
            gemmv2<0><<<dim3((MROWS / 128) * (NCHUNK / 128), 1), 256, 0, stream>>>(
                xfbuf, wbuf, nullptr, nullptr, outF + n0, nullptr, MROWS, NCHUNK, DMODEL, DMODEL, NVOCAB);
        }
    }
}

// Round 13
// 1306.389 us; speedup vs baseline: 2.7229x; 1.0514x over previous
//
#include <hip/hip_runtime.h>
#include <cstdint>
#include <cstddef>

// ---------------- constants ----------------
#define MROWS   4096      // B*T
#define TSEQ    2048
#define DMODEL  1024
#define NHEAD   16
#define FFN     4096
#define NVOCAB  32000
#define NLAYER  4

typedef float  f32x4  __attribute__((ext_vector_type(4)));
typedef __bf16 bf16x8 __attribute__((ext_vector_type(8)));

#define VMCNT(n) asm volatile("s_waitcnt vmcnt(" #n ")" ::: "memory")
#define LGKM0()  asm volatile("s_waitcnt lgkmcnt(0)" ::: "memory")

__device__ __forceinline__ unsigned short f2bf(float f) {
    unsigned u = __builtin_bit_cast(unsigned, f);
    u += 0x7fffu + ((u >> 16) & 1u);
    return (unsigned short)(u >> 16);
}
__device__ __forceinline__ float bf2f(unsigned short u) {
    return __builtin_bit_cast(float, (unsigned)u << 16);
}

__device__ __forceinline__ float gelu_exact(float v) {
    return 0.5f * v * (1.0f + erff(v * 0.7071067811865476f));
}

// ---------------- embedding ----------------
__global__ __launch_bounds__(256) void embed_kernel(const int* __restrict__ idx,
                                                    const float* __restrict__ tok,
                                                    const float* __restrict__ pos,
                                                    float* __restrict__ x) {
    int row = blockIdx.x, tid = threadIdx.x;
    int token = idx[row];
    int t = row & (TSEQ - 1);
    float4 a = ((const float4*)(tok + (size_t)token * DMODEL))[tid];
    float4 p = ((const float4*)(pos + (size_t)t * DMODEL))[tid];
    a.x += p.x; a.y += p.y; a.z += p.z; a.w += p.w;
    ((float4*)(x + (size_t)row * DMODEL))[tid] = a;
}

// ---------------- LayerNorm fp32 in -> bf16 out ----------------
__global__ __launch_bounds__(256) void ln_kernel(const float* __restrict__ x,
                                                 const float* __restrict__ g,
                                                 const float* __restrict__ b,
                                                 unsigned short* __restrict__ out) {
    int row = blockIdx.x, tid = threadIdx.x;
    float4 v = ((const float4*)(x + (size_t)row * DMODEL))[tid];
    float s1 = v.x + v.y + v.z + v.w;
    float s2 = v.x * v.x + v.y * v.y + v.z * v.z + v.w * v.w;
    for (int s = 32; s; s >>= 1) { s1 += __shfl_xor(s1, s); s2 += __shfl_xor(s2, s); }
    __shared__ float red[8];
    int lane = tid & 63, w = tid >> 6;
    if (lane == 0) { red[w] = s1; red[4 + w] = s2; }
    __syncthreads();
    s1 = red[0] + red[1] + red[2] + red[3];
    s2 = red[4] + red[5] + red[6] + red[7];
    float mean = s1 * (1.0f / DMODEL);
    float var  = s2 * (1.0f / DMODEL) - mean * mean;
    float rs   = rsqrtf(var + 1e-5f);
    float4 gv = ((const float4*)g)[tid];
    float4 bv = ((const float4*)b)[tid];
    size_t o = (size_t)row * DMODEL + tid * 4;
    out[o + 0] = f2bf((v.x - mean) * rs * gv.x + bv.x);
    out[o + 1] = f2bf((v.y - mean) * rs * gv.y + bv.y);
    out[o + 2] = f2bf((v.z - mean) * rs * gv.z + bv.z);
    out[o + 3] = f2bf((v.w - mean) * rs * gv.w + bv.w);
}

// ---------------- fast transpose + fp32->bf16: W[K][N](ldW) -> WT[N][K] ----------------
__global__ __launch_bounds__(256) void transpose_bf16(const float* __restrict__ W,
                                                      unsigned short* __restrict__ WT,
                                                      int K, int ldW) {
    __shared__ float tile[64][65];
    int n0 = blockIdx.x * 64, k0 = blockIdx.y * 64;
    int tid = threadIdx.x;
    int lr4 = tid & 15;
    int rw  = tid >> 4;
#pragma unroll
    for (int p = 0; p < 4; ++p) {
        int k = rw + p * 16;
        float4 v = *(const float4*)(W + (size_t)(k0 + k) * ldW + n0 + lr4 * 4);
        tile[k][lr4 * 4 + 0] = v.x;
        tile[k][lr4 * 4 + 1] = v.y;
        tile[k][lr4 * 4 + 2] = v.z;
        tile[k][lr4 * 4 + 3] = v.w;
    }
    __syncthreads();
    int kc = tid & 15;
    int nr = tid >> 4;
#pragma unroll
    for (int p = 0; p < 4; ++p) {
        int n = nr + p * 16;
        ushort4 o;
        o.x = f2bf(tile[kc * 4 + 0][n]);
        o.y = f2bf(tile[kc * 4 + 1][n]);
        o.z = f2bf(tile[kc * 4 + 2][n]);
        o.w = f2bf(tile[kc * 4 + 3][n]);
        *(ushort4*)(WT + (size_t)(n0 + n) * K + k0 + kc * 4) = o;
    }
}

// fused QKV transpose: z selects Wq/Wk/Wv, writes into 3-stacked WT
__global__ __launch_bounds__(256) void transpose_qkv(const float* __restrict__ Wq,
                                                     const float* __restrict__ Wk,
                                                     const float* __restrict__ Wv,
                                                     unsigned short* __restrict__ WT) {
    __shared__ float tile[64][65];
    const float* W = (blockIdx.z == 0) ? Wq : (blockIdx.z == 1) ? Wk : Wv;
    unsigned short* dst = WT + (size_t)blockIdx.z * DMODEL * DMODEL;
    int n0 = blockIdx.x * 64, k0 = blockIdx.y * 64;
    int tid = threadIdx.x;
    int lr4 = tid & 15, rw = tid >> 4;
#pragma unroll
    for (int p = 0; p < 4; ++p) {
        int k = rw + p * 16;
        float4 v = *(const float4*)(W + (size_t)(k0 + k) * DMODEL + n0 + lr4 * 4);
        tile[k][lr4 * 4 + 0] = v.x;
        tile[k][lr4 * 4 + 1] = v.y;
        tile[k][lr4 * 4 + 2] = v.z;
        tile[k][lr4 * 4 + 3] = v.w;
    }
    __syncthreads();
    int kc = tid & 15, nr = tid >> 4;
#pragma unroll
    for (int p = 0; p < 4; ++p) {
        int n = nr + p * 16;
        ushort4 o;
        o.x = f2bf(tile[kc * 4 + 0][n]);
        o.y = f2bf(tile[kc * 4 + 1][n]);
        o.z = f2bf(tile[kc * 4 + 2][n]);
        o.w = f2bf(tile[kc * 4 + 3][n]);
        *(ushort4*)(dst + (size_t)(n0 + n) * DMODEL + k0 + kc * 4) = o;
    }
}

// ---------------- pack fused QKV bias for all layers ----------------
__global__ __launch_bounds__(256) void pack_qkv_bias(const float* __restrict__ bq,
                                                     const float* __restrict__ bk,
                                                     const float* __restrict__ bv,
                                                     float* __restrict__ dst) {
    int i = blockIdx.x * 256 + threadIdx.x;
    int l = i / 3072, c = i % 3072;
    float v = (c < 1024) ? bq[l * 1024 + c]
            : (c < 2048) ? bk[l * 1024 + c - 1024]
                         : bv[l * 1024 + c - 2048];
    dst[i] = v;
}

// ---------------- split-K combine: x += p0 + p1 + bias ----------------
__global__ __launch_bounds__(256) void combine2(const float* __restrict__ p0,
                                                const float* __restrict__ p1,
                                                const float* __restrict__ bias,
                                                float* __restrict__ x) {
    int i = blockIdx.x * 256 + threadIdx.x;              // float4 index
    float4 a = ((const float4*)p0)[i];
    float4 b = ((const float4*)p1)[i];
    float4 xv = ((float4*)x)[i];
    int col = (i * 4) & (DMODEL - 1);
    float4 bb = *(const float4*)(bias + col);
    xv.x += a.x + b.x + bb.x;
    xv.y += a.y + b.y + bb.y;
    xv.z += a.z + b.z + bb.z;
    xv.w += a.w + b.w + bb.w;
    ((float4*)x)[i] = xv;
}

// ---------------- band attention (width-3), bf16 qkv in ----------------
__global__ __launch_bounds__(256) void attn_kernel(const unsigned short* __restrict__ qkv,
                                                   unsigned short* __restrict__ y) {
    int wid  = (blockIdx.x * 256 + threadIdx.x) >> 6;
    int lane = threadIdx.x & 63;
    int h = wid & (NHEAD - 1);
    int row = wid >> 4;
    int t = row & (TSEQ - 1);
    const unsigned short* base = qkv + (size_t)row * 3072 + h * 64;
    float qd = bf2f(base[lane]);
    float d0 = qd * bf2f(base[1024 + lane]);
    float d1 = (t >= 1) ? qd * bf2f(base[1024 - 3072 + lane]) : 0.0f;
    float d2 = (t >= 2) ? qd * bf2f(base[1024 - 6144 + lane]) : 0.0f;
    for (int s = 32; s; s >>= 1) {
        d0 += __shfl_xor(d0, s); d1 += __shfl_xor(d1, s); d2 += __shfl_xor(d2, s);
    }
    d0 *= 0.125f; d1 *= 0.125f; d2 *= 0.125f;
    float m = d0;
    if (t >= 1) m = fmaxf(m, d1);
    if (t >= 2) m = fmaxf(m, d2);
    float p0 = expf(d0 - m);
    float p1 = (t >= 1) ? expf(d1 - m) : 0.0f;
    float p2 = (t >= 2) ? expf(d2 - m) : 0.0f;
    float den = p0 + p1 + p2;
    float v0 = bf2f(base[2048 + lane]);
    float v1 = (t >= 1) ? bf2f(base[2048 - 3072 + lane]) : 0.0f;
    float v2 = (t >= 2) ? bf2f(base[2048 - 6144 + lane]) : 0.0f;
    float yv = (p0 * v0 + p1 * v1 + p2 * v2) / den;
    y[(size_t)row * DMODEL + h * 64 + lane] = f2bf(yv);
}

// ======================================================================
// gemmv2: 128x128 tile, 256 threads / 4 waves, BK=32, 2 LDS buffers
// (32 KB) -> 3 blocks/CU.  Packed-line zero-conflict LDS layout.
// EPI: 0=raw f32 partial, 1=bias+res->f32, 2=gelu(bias)->bf16, 3=bias->bf16
// ======================================================================
template <int EPI>
__global__ __launch_bounds__(256, 3) void gemmv2(const unsigned short* __restrict__ A,
                                                 const unsigned short* __restrict__ BT,
                                                 const float* __restrict__ bias,
                                                 const float* __restrict__ res,
                                                 float* __restrict__ outF,
                                                 unsigned short* __restrict__ outB,
                                                 int M, int N, int Ks, int KL, int ldc) {
    __shared__ unsigned short As[2][4096];
    __shared__ unsigned short Bs[2][4096];
    const int tid = threadIdx.x;
    const int lane = tid & 63, wid = tid >> 6;
    const int wr = wid >> 1, wc = wid & 1;       // 2x2 waves, wave tile 64x64
    const int lr = lane & 15, kq = lane >> 4;

    const int nbm = M >> 7;
    const int nwg = gridDim.x;
    int orig = blockIdx.x;
    int q8 = nwg >> 3, r8 = nwg & 7;
    int xcd = orig & 7, lin = orig >> 3;
    int wg = (xcd < r8 ? xcd * (q8 + 1) : r8 * (q8 + 1) + (xcd - r8) * q8) + lin;
    int bm = wg % nbm, bn = wg / nbm;
    const int kc = blockIdx.y;

    const unsigned short* Ab = A + (size_t)bm * 128 * Ks + (size_t)kc * KL;
    const unsigned short* Bb = BT + (size_t)bn * 128 * Ks + (size_t)kc * KL;

    int sOff[2];
#pragma unroll
    for (int i = 0; i < 2; ++i) {
        int pc = i * 256 + tid;
        int line = pc >> 3, slot = pc & 7;
        int row = line * 2 + (slot >> 2);
        int c = (slot & 3) ^ (line & 3);
        sOff[i] = row * Ks + c * 8;
    }

#define STAGEV2(T) do {                                                                        \
    unsigned short* dA_ = &As[(T) & 1][0];                                                     \
    unsigned short* dB_ = &Bs[(T) & 1][0];                                                     \
    _Pragma("unroll") for (int i_ = 0; i_ < 2; ++i_) {                                         \
        __builtin_amdgcn_global_load_lds(                                                      \
            (const __attribute__((address_space(1))) void*)(Ab + sOff[i_] + (T) * 32),         \
            (__attribute__((address_space(3))) void*)(dA_ + (size_t)(i_ * 256 + tid) * 8), 16, 0, 0); \
        __builtin_amdgcn_global_load_lds(                                                      \
            (const __attribute__((address_space(1))) void*)(Bb + sOff[i_] + (T) * 32),         \
            (__attribute__((address_space(3))) void*)(dB_ + (size_t)(i_ * 256 + tid) * 8), 16, 0, 0); \
    }                                                                                          \
} while (0)

    const int slot = ((lane & 1) << 2) | (kq ^ ((lr >> 1) & 3));
    const int laneOff = ((lr >> 1) << 6) + slot * 8;
    int aOff[4], bOff[4];
#pragma unroll
    for (int m = 0; m < 4; ++m) aOff[m] = wr * 2048 + m * 512 + laneOff;
#pragma unroll
    for (int n = 0; n < 4; ++n) bOff[n] = wc * 2048 + n * 512 + laneOff;

    f32x4 acc[4][4] = {};
    const int nt = KL >> 5;

    STAGEV2(0);
    __syncthreads();

    for (int t = 0; t < nt; ++t) {
        const bool pf = (t + 1) < nt;
        if (pf) STAGEV2(t + 1);
        const unsigned short* sA = &As[t & 1][0];
        const unsigned short* sB = &Bs[t & 1][0];
        bf16x8 a[4], b[4];
#pragma unroll
        for (int m = 0; m < 4; ++m) a[m] = *(const bf16x8*)(sA + aOff[m]);
#pragma unroll
        for (int n = 0; n < 4; ++n) b[n] = *(const bf16x8*)(sB + bOff[n]);
        __builtin_amdgcn_s_setprio(1);
#pragma unroll
        for (int m = 0; m < 4; ++m)
#pragma unroll
            for (int n = 0; n < 4; ++n)
                acc[m][n] = __builtin_amdgcn_mfma_f32_16x16x32_bf16(a[m], b[n], acc[m][n], 0, 0, 0);
        __builtin_amdgcn_s_setprio(0);
        if (pf) __syncthreads();
    }

    const int row0 = bm * 128 + wr * 64;
    const int col0 = bn * 128 + wc * 64;
    float* outP = (EPI == 0) ? (outF + (size_t)kc * M * ldc) : outF;
#pragma unroll
    for (int m = 0; m < 4; ++m) {
#pragma unroll
        for (int n = 0; n < 4; ++n) {
            int col = col0 + n * 16 + lr;
            int rbase = row0 + m * 16 + kq * 4;
            float bb = (EPI != 0 && bias) ? bias[col] : 0.0f;
#pragma unroll
            for (int j = 0; j < 4; ++j) {
                size_t off = (size_t)(rbase + j) * ldc + col;
                float v = acc[m][n][j] + bb;
                if (EPI == 1) v += res[off];
                if (EPI == 2)      outB[off] = f2bf(gelu_exact(v));
                else if (EPI == 3) outB[off] = f2bf(v);
                else               outP[off] = v;
            }
        }
    }
#undef STAGEV2
}

// ======================================================================
// gemm256lp: 256x256, BK=64 (2 K-half regions), 8 waves, LOW-SYNC
// 2-phase schedule: per K-tile only 2 barriers + 2 counted vmcnt +
// 2 lgkm drains (vs 8/2/4 in R9).  Phase = {vmcnt(4); barrier;
// 12 ds_reads; stage 2 regions of t+1; lgkm0; setprio; 32 MFMA}.
// Ledger: 8 loads outstanding steady-state; vmcnt(4) waits exactly the
// half being consumed; drain to 0 only in the last tile's phase B.
// Overwrite safety: >=2 barriers between last read and restage; each
// wave lgkm0-drains its own reads before reaching the next barrier.
// Packed-line zero-conflict LDS layout (R9-verified). EPI0 (f32 out).
// ======================================================================
__global__ __launch_bounds__(512, 2) void gemm256lp(const unsigned short* __restrict__ A,
                                                    const unsigned short* __restrict__ BT,
                                                    float* __restrict__ outF,
                                                    int M, int N, int K, int ldc) {
    __shared__ unsigned short As[2][2][8192];   // [dbuf][khalf][256r x 32k packed]
    __shared__ unsigned short Bs[2][2][8192];
    const int tid = threadIdx.x;
    const int lane = tid & 63, wid = tid >> 6;
    const int wr = wid >> 2, wc = wid & 3;       // wave tile 128x64
    const int lr = lane & 15, kq = lane >> 4;

    const int nbm = M >> 8;
    const int nwg = gridDim.x;
    int orig = blockIdx.x;
    int q8 = nwg >> 3, r8 = nwg & 7;
    int xcd = orig & 7, lin = orig >> 3;
    int wg = (xcd < r8 ? xcd * (q8 + 1) : r8 * (q8 + 1) + (xcd - r8) * q8) + lin;
    int bm = wg % nbm, bn = wg / nbm;

    const unsigned short* Ab = A + (size_t)bm * 256 * K;
    const unsigned short* Bb = BT + (size_t)bn * 256 * K;

    int sG0, sG1;
    {
        int pc0 = tid,        l0 = pc0 >> 3, s0 = pc0 & 7;
        int pc1 = 512 + tid,  l1 = pc1 >> 3, s1 = pc1 & 7;
        sG0 = (l0 * 2 + (s0 >> 2)) * K + (((s0 & 3) ^ (l0 & 3)) * 8);
        sG1 = (l1 * 2 + (s1 >> 2)) * K + (((s1 & 3) ^ (l1 & 3)) * 8);
    }

#define STAGE256(REGION, GBASE, TT, KH) do {                                                   \
    __builtin_amdgcn_global_load_lds(                                                          \
        (const __attribute__((address_space(1))) void*)((GBASE) + sG0 + (TT) * 64 + (KH) * 32),\
        (__attribute__((address_space(3))) void*)((REGION) + (size_t)tid * 8), 16, 0, 0);      \
    __builtin_amdgcn_global_load_lds(                                                          \
        (const __attribute__((address_space(1))) void*)((GBASE) + sG1 + (TT) * 64 + (KH) * 32),\
        (__attribute__((address_space(3))) void*)((REGION) + (size_t)(512 + tid) * 8), 16, 0, 0);\
} while (0)

    const int slot = ((lane & 1) << 2) | (kq ^ ((lr >> 1) & 3));
    const int laneOff = ((lr >> 1) << 6) + slot * 8;
    const int aBase = wr * 4096 + laneOff;       // + m*512
    const int bBase = wc * 2048 + laneOff;       // + n*512

    f32x4 acc[8][4] = {};
    const int nt = K >> 6;

    // prologue: tile 0, stage order = steady-state order (A0,B0 then A1,B1)
    STAGE256(&As[0][0][0], Ab, 0, 0);
    STAGE256(&Bs[0][0][0], Bb, 0, 0);
    STAGE256(&As[0][1][0], Ab, 0, 1);
    STAGE256(&Bs[0][1][0], Bb, 0, 1);

    for (int t = 0; t < nt; ++t) {
        const int buf = t & 1;
        const bool pf = (t + 1) < nt;

        // ---- phase A (kh0): consume A0,B0(t); stage A0',B0'(t+1) ----
        VMCNT(4);                       // oldest 4 = A0,B0 of tile t
        __builtin_amdgcn_s_barrier();
        {
            const unsigned short* A0 = &As[buf][0][0];
            const unsigned short* B0 = &Bs[buf][0][0];
            bf16x8 a[8], b[4];
#pragma unroll
            for (int m = 0; m < 8; ++m) a[m] = *(const bf16x8*)(A0 + aBase + m * 512);
#pragma unroll
            for (int n = 0; n < 4; ++n) b[n] = *(const bf16x8*)(B0 + bBase + n * 512);
            if (pf) {
                STAGE256(&As[buf ^ 1][0][0], Ab, t + 1, 0);
                STAGE256(&Bs[buf ^ 1][0][0], Bb, t + 1, 0);
            }
            LGKM0();
            __builtin_amdgcn_s_setprio(1);
#pragma unroll
            for (int m = 0; m < 8; ++m)
#pragma unroll
                for (int n = 0; n < 4; ++n)
                    acc[m][n] = __builtin_amdgcn_mfma_f32_16x16x32_bf16(a[m], b[n], acc[m][n], 0, 0, 0);
            __builtin_amdgcn_s_setprio(0);
        }

        // ---- phase B (kh1): consume A1,B1(t); stage A1',B1'(t+1) ----
        if (pf) VMCNT(4); else VMCNT(0);
        __builtin_amdgcn_s_barrier();
        {
            const unsigned short* A1 = &As[buf][1][0];
            const unsigned short* B1 = &Bs[buf][1][0];
            bf16x8 a[8], b[4];
#pragma unroll
            for (int m = 0; m < 8; ++m) a[m] = *(const bf16x8*)(A1 + aBase + m * 512);
#pragma unroll
            for (int n = 0; n < 4; ++n) b[n] = *(const bf16x8*)(B1 + bBase + n * 512);
            if (pf) {
                STAGE256(&As[buf ^ 1][1][0], Ab, t + 1, 1);
                STAGE256(&Bs[buf ^ 1][1][0], Bb, t + 1, 1);
            }
            LGKM0();
            __builtin_amdgcn_s_setprio(1);
#pragma unroll
            for (int m = 0; m < 8; ++m)
#pragma unroll
                for (int n = 0; n < 4; ++n)
                    acc[m][n] = __builtin_amdgcn_mfma_f32_16x16x32_bf16(a[m], b[n], acc[m][n], 0, 0, 0);
            __builtin_amdgcn_s_setprio(0);
        }
    }

    // epilogue (verified mapping: col=lane&15, row=kq*4+j)
    const int row0 = bm * 256 + wr * 128;
    const int col0 = bn * 256 + wc * 64;
#pragma unroll
    for (int m = 0; m < 8; ++m) {
#pragma unroll
        for (int n = 0; n < 4; ++n) {
            int col = col0 + n * 16 + lr;
            int rbase = row0 + m * 16 + kq * 4;
#pragma unroll
            for (int j = 0; j < 4; ++j) {
                size_t off = (size_t)(rbase + j) * ldc + col;
                outF[off] = acc[m][n][j];
            }
        }
    }
#undef STAGE256
}

// ---------------- host launch ----------------
extern "C" void kernel_launch(void* const* d_in, const int* in_sizes, int n_in,
                              void* d_out, int out_size, void* d_ws, size_t ws_size,
                              hipStream_t stream) {
    const int*   idx  = (const int*)d_in[0];
    const float* tok  = (const float*)d_in[1];
    const float* pos  = (const float*)d_in[2];
    const float* Wq   = (const float*)d_in[3];
    const float* bq   = (const float*)d_in[4];
    const float* Wk   = (const float*)d_in[5];
    const float* bk   = (const float*)d_in[6];
    const float* Wv   = (const float*)d_in[7];
    const float* bv   = (const float*)d_in[8];
    const float* Wo   = (const float*)d_in[9];
    const float* bo   = (const float*)d_in[10];
    const float* ln1g = (const float*)d_in[11];
    const float* ln1b = (const float*)d_in[12];
    const float* W1   = (const float*)d_in[13];
    const float* b1   = (const float*)d_in[14];
    const float* W2   = (const float*)d_in[15];
    const float* b2   = (const float*)d_in[16];
    const float* ln2g = (const float*)d_in[17];
    const float* ln2b = (const float*)d_in[18];
    const float* lnfg = (const float*)d_in[19];
    const float* lnfb = (const float*)d_in[20];
    const float* lmW  = (const float*)d_in[21];

    const bool bigws = ws_size >= (92ull << 20);

    char* ws = (char*)d_ws;
    unsigned short* wbuf;
    unsigned short* hbuf;
    unsigned short* ybuf;
    unsigned short* xfbuf;
    float*          bqkv;
    if (bigws) {
        wbuf  = (unsigned short*)(ws);
        hbuf  = (unsigned short*)(ws + (63ull << 20));
        ybuf  = (unsigned short*)(ws + (71ull << 20));
        xfbuf = (unsigned short*)(ws + (79ull << 20));
        bqkv  = (float*)(ws + (87ull << 20));
    } else {
        wbuf  = (unsigned short*)(ws);
        hbuf  = (unsigned short*)(ws + (16u << 20));
        ybuf  = (unsigned short*)(ws + (24u << 20));
        xfbuf = (unsigned short*)(ws + (32u << 20));
        bqkv  = (float*)(ws + (40u << 20));
    }

    // scratch inside d_out (dead before LM-head GEMM overwrites all of d_out)
    float* outF = (float*)d_out;
    float* xbuf = outF;                                                        // [0,16) MiB residual fp32
    unsigned short* qkv = (unsigned short*)((char*)d_out + (16ull << 20));     // [16,40) MiB bf16 qkv
    unsigned short* hidden = (unsigned short*)((char*)d_out + (64ull << 20));  // [64,96) MiB bf16 hidden
    float* pbuf = (float*)((char*)d_out + (96ull << 20));                      // [96,128) MiB split-K partials

    embed_kernel<<<MROWS, 256, 0, stream>>>(idx, tok, pos, xbuf);
    pack_qkv_bias<<<(NLAYER * 3072) / 256, 256, 0, stream>>>(bq, bk, bv, bqkv);

    for (int l = 0; l < NLAYER; l++) {
        const size_t wl = (size_t)l * DMODEL * DMODEL;
        ln_kernel<<<MROWS, 256, 0, stream>>>(xbuf, ln1g + l * DMODEL, ln1b + l * DMODEL, hbuf);

        // QKV: gemmv2 EPI3 (grid 768 = 3 blocks/CU exactly)
        transpose_qkv<<<dim3(16, 16, 3), 256, 0, stream>>>(Wq + wl, Wk + wl, Wv + wl, wbuf);
        gemmv2<3><<<dim3((MROWS / 128) * (3072 / 128), 1), 256, 0, stream>>>(
            hbuf, wbuf, bqkv + l * 3072, nullptr, nullptr, qkv, MROWS, 3072, DMODEL, DMODEL, 3072);

        attn_kernel<<<MROWS * NHEAD / 4, 256, 0, stream>>>(qkv, ybuf);

        // Wo: gemmv2 fused bias+res
        transpose_bf16<<<dim3(16, 16), 256, 0, stream>>>(Wo + wl, wbuf, DMODEL, DMODEL);
        gemmv2<1><<<dim3((MROWS / 128) * (DMODEL / 128), 1), 256, 0, stream>>>(
            ybuf, wbuf, bo + l * DMODEL, xbuf, xbuf, nullptr, MROWS, DMODEL, DMODEL, DMODEL, DMODEL);

        ln_kernel<<<MROWS, 256, 0, stream>>>(xbuf, ln2g + l * DMODEL, ln2b + l * DMODEL, hbuf);

        // W1: gemmv2 gelu
        transpose_bf16<<<dim3(FFN / 64, DMODEL / 64), 256, 0, stream>>>(W1 + (size_t)l * DMODEL * FFN, wbuf, DMODEL, FFN);
        gemmv2<2><<<dim3((MROWS / 128) * (FFN / 128), 1), 256, 0, stream>>>(
            hbuf, wbuf, b1 + l * FFN, nullptr, nullptr, hidden, MROWS, FFN, DMODEL, DMODEL, FFN);

        // W2: gemmv2 split-K=2 + combine
        transpose_bf16<<<dim3(DMODEL / 64, FFN / 64), 256, 0, stream>>>(W2 + (size_t)l * FFN * DMODEL, wbuf, FFN, DMODEL);
        gemmv2<0><<<dim3((MROWS / 128) * (DMODEL / 128), 2), 256, 0, stream>>>(
            hidden, wbuf, nullptr, nullptr, pbuf, nullptr, MROWS, DMODEL, FFN, FFN / 2, DMODEL);
        combine2<<<MROWS * DMODEL / 4 / 256, 256, 0, stream>>>(
            pbuf, pbuf + (size_t)MROWS * DMODEL, b2 + l * DMODEL, xbuf);
    }

    ln_kernel<<<MROWS, 256, 0, stream>>>(xbuf, lnfg, lnfb, xfbuf);

    if (bigws) {
        transpose_bf16<<<dim3(NVOCAB / 64, DMODEL / 64), 256, 0, stream>>>(lmW, wbuf, DMODEL, NVOCAB);
        gemm256lp<<<dim3((NVOCAB / 256) * (MROWS / 256)), 512, 0, stream>>>(
            xfbuf, wbuf, outF, MROWS, NVOCAB, DMODEL, NVOCAB);
    } else {
        const int NCHUNK = 6400;
        for (int c = 0; c < NVOCAB / NCHUNK; c++) {
            int n0 = c * NCHUNK;
            transpose_bf16<<<dim3(NCHUNK / 64, DMODEL / 64), 256, 0, stream>>>(lmW + n0, wbuf, DMODEL, NVOCAB);
            gemm256lp<<<dim3((NCHUNK / 256) * (MROWS / 256)), 512, 0, stream>>>(
                xfbuf, wbuf, outF + n0, MROWS, NCHUNK, DMODEL, NVOCAB);
        }
    }
}